// Round 15
// baseline (233.629 us; speedup 1.0000x reference)
//
#include <hip/hip_runtime.h>
#include <hip/hip_bf16.h>

#define NTOK   65536
#define KCODES 1024
#define DIM    256
#define LOSS_OFF ((size_t)NTOK * DIM)
#define IDX_OFF  (LOSS_OFF + 1)

#define MARGA 2e-4f     // a-space margin (validated rounds 8/10/12)

// ---- scratch layout inside the z_q output region (float-slot offsets) ----
#define SC_ZSQ    0              // 65536 f
#define SC_LOSS2  131072         // 65536 f
#define SC_ESQ    196608         // 1024 f
#define SC_ESQNH  197632         // 1024 f
#define SC_PART   198656         // 64 f
#define SC_WCNT   198720         // 1 int
#define SC_WCNT2  198721         // 1 int
#define SC_CNTG   198784         // 65536 int
#define SC_LISTS  264320         // 524288 int (8 per token)
#define SC_WLIST  788608         // 65536 int
#define SC_WLIST2 854144         // 4096 int
#define SC_EHIMG  858240         // 131072 f-slots = 512 KB bf16 emb image
#define SC_ZIMG   989312         // 8388608 f-slots = 32 MB bf16 z image (frag layout)
#define SC_PAIRD  9377920        // 524288 f (per-pair faithful distances)

typedef __attribute__((ext_vector_type(8))) short short8;
typedef __attribute__((ext_vector_type(4))) float f32x4;

__device__ __forceinline__ unsigned f2bf(float x) {
    unsigned u = __float_as_uint(x);
    return (u + 0x7FFFu + ((u >> 16) & 1u)) >> 16;   // RNE
}

__device__ __forceinline__ void gload16(const void* g, void* l) {
    __builtin_amdgcn_global_load_lds((const __attribute__((address_space(1))) unsigned int*)g,
                                     (__attribute__((address_space(3))) unsigned int*)l,
                                     16, 0, 0);
}

// faithful fp32 distance (validated rounds 4-12): sequential single-acc FMA chain
__device__ __forceinline__ float faithful_d(const float* __restrict__ z,
                                            const float* __restrict__ emb,
                                            float zsq, float esq, int tok, int c) {
    const float4* zr = (const float4*)(z + (size_t)tok * DIM);
    const float4* er = (const float4*)(emb + (size_t)c * DIM);
    float acc = 0.f;
#pragma unroll 8
    for (int q = 0; q < 64; ++q) {
        float4 a = zr[q], b = er[q];
        acc = fmaf(a.x, b.x, acc); acc = fmaf(a.y, b.y, acc);
        acc = fmaf(a.z, b.z, acc); acc = fmaf(a.w, b.w, acc);
    }
    float t1 = zsq + esq;
    return t1 - 2.0f * acc;
}

// wave-parallel numpy pairwise sum-of-squares replica (16 lanes per 256-row)
__device__ __forceinline__ float np_rowsq256_wave(const float* row, int sub) {
    const int j = sub & 7, half = sub >> 3;
    const float* a = row + half * 128 + j;
    float r = 0.f;
#pragma unroll
    for (int i = 0; i < 16; ++i) {
        float v = a[i * 8];
        float sq = v * v;
        asm volatile("" : "+v"(sq));
        r += sq;
    }
    float t = r + __shfl_xor(r, 1, 64);
    t = t + __shfl_xor(t, 2, 64);
    t = t + __shfl_xor(t, 4, 64);
    t = t + __shfl_xor(t, 8, 64);
    return t;
}

// ---------------- prep: esq / esqnh (+ worklist counters reset) ----------------
__global__ __launch_bounds__(256) void vq_prep_esq(const float* __restrict__ emb,
                                                   float* __restrict__ esq,
                                                   float* __restrict__ esqnh,
                                                   int* __restrict__ wcnt,
                                                   int* __restrict__ wcnt2) {
    if (blockIdx.x == 0 && threadIdx.x == 0) { *wcnt = 0; *wcnt2 = 0; }
    int code = blockIdx.x * 16 + (threadIdx.x >> 4);   // grid 64
    int sub = threadIdx.x & 15;
    float tot = np_rowsq256_wave(emb + (size_t)code * DIM, sub);
    if (sub == 0) { esq[code] = tot; esqnh[code] = -0.5f * tot; }
}

// ---------------- prep: zsq (np-faithful) + bf16 z image in MFMA-fragment layout ----------------
__global__ __launch_bounds__(256) void vq_prep_z(const float* __restrict__ z,
                                                 float* __restrict__ zsq,
                                                 unsigned short* __restrict__ zimg) {
    int tok = blockIdx.x * 16 + (threadIdx.x >> 4);    // grid 4096
    int sub = threadIdx.x & 15;
    float tot = np_rowsq256_wave(z + (size_t)tok * DIM, sub);
    if (sub == 0) zsq[tok] = tot;

    const float* src = z + (size_t)tok * DIM + sub * 16;
    float4 v0 = *(const float4*)&src[0],  v1 = *(const float4*)&src[4];
    float4 v2 = *(const float4*)&src[8],  v3 = *(const float4*)&src[12];
    uint4 p0, p1;
    p0.x = f2bf(v0.x) | (f2bf(v0.y) << 16);  p0.y = f2bf(v0.z) | (f2bf(v0.w) << 16);
    p0.z = f2bf(v1.x) | (f2bf(v1.y) << 16);  p0.w = f2bf(v1.z) | (f2bf(v1.w) << 16);
    p1.x = f2bf(v2.x) | (f2bf(v2.y) << 16);  p1.y = f2bf(v2.z) | (f2bf(v2.w) << 16);
    p1.z = f2bf(v3.x) | (f2bf(v3.y) << 16);  p1.w = f2bf(v3.z) | (f2bf(v3.w) << 16);

    int bid = tok >> 6, tf = (tok >> 4) & 3, sl = tok & 15;
    int g0 = sub * 2, g1 = g0 + 1;
    size_t rowbase = ((size_t)bid * 4 + tf) * 8;
    char* d0 = (char*)zimg + ((rowbase + (g0 >> 2)) << 10) + (((g0 & 3) * 16 + sl) << 4);
    char* d1 = (char*)zimg + ((rowbase + (g1 >> 2)) << 10) + (((g1 & 3) * 16 + sl) << 4);
    *(uint4*)d0 = p0;
    *(uint4*)d1 = p1;
}

// ---------------- prep: bf16 emb image in pre-swizzled LDS slice layout ----------------
__global__ __launch_bounds__(256) void vq_prep_eimg(const float* __restrict__ emb,
                                                    unsigned short* __restrict__ img) {
    int job = blockIdx.x * 256 + threadIdx.x;   // grid 32
    int code = job >> 3, ks = job & 7;
    int cc = (code >> 6) & 3, lcl = (code >> 8) * 64 + (code & 63);
    const float* src = emb + (size_t)code * DIM + ks * 32;
    char* base = (char*)img + (size_t)(cc * 8 + ks) * 16384;
#pragma unroll
    for (int q = 0; q < 4; ++q) {
        float4 v0 = *(const float4*)&src[q * 8];
        float4 v1 = *(const float4*)&src[q * 8 + 4];
        uint4 p;
        p.x = f2bf(v0.x) | (f2bf(v0.y) << 16);
        p.y = f2bf(v0.z) | (f2bf(v0.w) << 16);
        p.z = f2bf(v1.x) | (f2bf(v1.y) << 16);
        p.w = f2bf(v1.z) | (f2bf(v1.w) << 16);
        *(uint4*)(base + lcl * 64 + ((q * 16) ^ (((lcl >> 1) & 3) << 4))) = p;
    }
}

// ---------------- SINGLE-PASS GEMM filter with speculative enumeration ----------------
// Each block covers ALL 1024 codes for its 64 tokens. Per c-tile fold: wave-local
// running max m_run (2 shuffles, no barrier), then enumerate acc >= m_run - MARGA
// into LDS lists WITH a-values. Superset property: m_run <= a1_final at all times,
// so every code with a >= a1_final - MARGA is captured. Epilogue filters against the
// true a1 (cross-wave merge). K-loop schedule = round-12 validated (__syncthreads/step).
__global__ __launch_bounds__(256, 2) void vq_gemm(const unsigned short* __restrict__ zimg,
                                                  const unsigned short* __restrict__ img,
                                                  const float* __restrict__ esqnh,
                                                  const float* __restrict__ zsq,
                                                  int* __restrict__ wcnt,
                                                  int* __restrict__ wlist,
                                                  int* __restrict__ cntg,
                                                  int* __restrict__ listsg,
                                                  float* __restrict__ loss2,
                                                  float* __restrict__ dout) {
    __shared__ __align__(16) short eh_s[2][8192];     // 2 x 16 KB (async-staged e image)
    __shared__ float a1w_s[4][64];                    // per-wave per-token maxes
    __shared__ int   cnt_s[64];
    __shared__ int   lists_s[64 * 16];                // speculative codes (4 KB)
    __shared__ float avals_s[64 * 16];                // their a-values (4 KB)

    const int tid = threadIdx.x, bid = blockIdx.x;
    const int w = tid >> 6, l = tid & 63;
    const int t0 = bid * 64;

    // z fragments -> registers (coalesced 1KB wave loads; layout validated rounds 11/12)
    short8 zf[4][8];
#pragma unroll
    for (int tf = 0; tf < 4; ++tf)
#pragma unroll
        for (int ks = 0; ks < 8; ++ks)
            zf[tf][ks] = *(const short8*)((const char*)zimg +
                           ((((size_t)bid * 4 + tf) * 8 + ks) << 10) + (size_t)l * 16);

    if (tid < 64) cnt_s[tid] = 0;
    // issue eh slice 0 (async -> eh_s[0])
    {
        const char* gs = (const char*)img + w * 4096 + (size_t)l * 16;
        char* ld = (char*)&eh_s[0][0] + w * 4096;
#pragma unroll
        for (int i = 0; i < 4; ++i) gload16(gs + i * 1024, ld + i * 1024);
    }
    __syncthreads();

    float m_run[4] = {-3.4e38f, -3.4e38f, -3.4e38f, -3.4e38f};
    f32x4 acc[4][4];

#pragma unroll
    for (int c = 0; c < 4; ++c) {
#pragma unroll
        for (int f = 0; f < 4; ++f) {
            f32x4 e4 = *(const f32x4*)&esqnh[w * 256 + c * 64 + f * 16 + (l >> 4) * 4];
#pragma unroll
            for (int tf = 0; tf < 4; ++tf) acc[f][tf] = e4;
        }
#pragma unroll
        for (int ks = 0; ks < 8; ++ks) {
            int s = c * 8 + ks, buf = s & 1;
            if (s < 31) {   // prefetch next slice async into other buffer
                const char* gs = (const char*)img + (size_t)(s + 1) * 16384 + w * 4096 + (size_t)l * 16;
                char* ld = (char*)&eh_s[buf ^ 1][0] + w * 4096;
#pragma unroll
                for (int i = 0; i < 4; ++i) gload16(gs + i * 1024, ld + i * 1024);
            }
            short8 afr[4];
#pragma unroll
            for (int f = 0; f < 4; ++f) {
                int lcl = w * 64 + f * 16 + (l & 15);
                int byte = lcl * 64 + (((l >> 4) * 16) ^ (((lcl >> 1) & 3) << 4));
                afr[f] = *(const short8*)((const char*)&eh_s[buf][0] + byte);
            }
#pragma unroll
            for (int f = 0; f < 4; ++f)
#pragma unroll
                for (int tf = 0; tf < 4; ++tf)
                    acc[f][tf] = __builtin_amdgcn_mfma_f32_16x16x32_bf16(
                        afr[f], zf[tf][ks], acc[f][tf], 0, 0, 0);
            __syncthreads();   // validated round-12 schedule (drains prefetch; no spill)
        }
        // fold: wave-local running max, then speculative enumerate with a-values
#pragma unroll
        for (int tf = 0; tf < 4; ++tf) {
            float m0 = fmaxf(fmaxf(acc[0][tf][0], acc[0][tf][1]), fmaxf(acc[0][tf][2], acc[0][tf][3]));
            float m1 = fmaxf(fmaxf(acc[1][tf][0], acc[1][tf][1]), fmaxf(acc[1][tf][2], acc[1][tf][3]));
            float m2 = fmaxf(fmaxf(acc[2][tf][0], acc[2][tf][1]), fmaxf(acc[2][tf][2], acc[2][tf][3]));
            float m3 = fmaxf(fmaxf(acc[3][tf][0], acc[3][tf][1]), fmaxf(acc[3][tf][2], acc[3][tf][3]));
            float tm = fmaxf(fmaxf(m0, m1), fmaxf(m2, m3));
            tm = fmaxf(tm, __shfl_xor(tm, 16, 64));
            tm = fmaxf(tm, __shfl_xor(tm, 32, 64));   // per-token max of this wave's 64-code tile
            m_run[tf] = fmaxf(m_run[tf], tm);
            float thr = m_run[tf] - MARGA;
            int tokl = tf * 16 + (l & 15);
#pragma unroll
            for (int f = 0; f < 4; ++f)
#pragma unroll
                for (int r = 0; r < 4; ++r) {
                    float a = acc[f][tf][r];
                    if (a >= thr) {
                        int code = w * 256 + c * 64 + f * 16 + (l >> 4) * 4 + r;
                        int pos = atomicAdd(&cnt_s[tokl], 1);
                        if (pos < 16) {
                            lists_s[tokl * 16 + pos] = code;
                            avals_s[tokl * 16 + pos] = a;
                        }
                    }
                }
        }
    }

    // cross-wave max merge
#pragma unroll
    for (int tf = 0; tf < 4; ++tf)
        if (l < 16) a1w_s[w][tf * 16 + l] = m_run[tf];
    __syncthreads();

    // epilogue: filter speculative lists against true a1; finalize or defer
    if (tid < 64) {
        int t = t0 + tid;
        float a1v = fmaxf(fmaxf(a1w_s[0][tid], a1w_s[1][tid]),
                          fmaxf(a1w_s[2][tid], a1w_s[3][tid]));
        int ct_raw = cnt_s[tid];
        if (ct_raw > 16) {              // list overflow -> exact full scan path
            int pos = atomicAdd(wcnt, 1);
            wlist[pos] = t;
            cntg[t] = 999;
        } else {
            float thr = a1v - MARGA;
            int kept = 0, first = 0;
            for (int i = 0; i < ct_raw; ++i) {
                float av = avals_s[tid * 16 + i];
                if (av >= thr) {
                    int code = lists_s[tid * 16 + i];
                    if (kept == 0) first = code;
                    if (kept < 8) listsg[(size_t)t * 8 + kept] = code;
                    ++kept;
                }
            }
            if (kept == 1) {
                dout[IDX_OFF + t] = (float)first;
                loss2[t] = fmaf(-2.f, a1v, zsq[t]);
            } else {
                int pos = atomicAdd(wcnt, 1);
                wlist[pos] = t;
                cntg[t] = (kept > 8) ? 999 : kept;
            }
        }
    }
}

// ---------------- pairs: one LANE per (hard-token, candidate) pair ----------------
__global__ __launch_bounds__(256) void vq_pairs(const float* __restrict__ z,
                                                const float* __restrict__ emb,
                                                const float* __restrict__ zsq,
                                                const float* __restrict__ esq,
                                                const int* __restrict__ wcnt,
                                                const int* __restrict__ wlist,
                                                const int* __restrict__ cntg,
                                                const int* __restrict__ listsg,
                                                int* __restrict__ wcnt2,
                                                int* __restrict__ wlist2,
                                                float* __restrict__ paird) {
    const int n = wcnt[0];
    const int total = 8 * n;
    for (int p = blockIdx.x * 256 + threadIdx.x; p < total; p += 2048 * 256) {
        int q = p >> 3, slot = p & 7;
        int tok = wlist[q];
        int ct = cntg[tok];
        if (ct == 0 || ct > 8) {
            if (slot == 0) {
                int pos = atomicAdd(wcnt2, 1);
                if (pos < 4096) wlist2[pos] = tok;
            }
            continue;
        }
        if (slot >= ct) continue;
        int code = listsg[(size_t)tok * 8 + slot];
        paird[p] = faithful_d(z, emb, zsq[tok], esq[code], tok, code);
    }
}

// ---------------- pick: thread per hard token, lexicographic (d, code) argmin ----------------
__global__ __launch_bounds__(256) void vq_pick(const float* __restrict__ paird,
                                               const int* __restrict__ wcnt,
                                               const int* __restrict__ wlist,
                                               const int* __restrict__ cntg,
                                               const int* __restrict__ listsg,
                                               float* __restrict__ loss2,
                                               float* __restrict__ dout) {
    const int n = wcnt[0];
    for (int q = blockIdx.x * 256 + threadIdx.x; q < n; q += 256 * 256) {
        int tok = wlist[q];
        int ct = cntg[tok];
        if (ct == 0 || ct > 8) continue;   // scan kernel owns these
        float db = paird[q * 8];
        int cb = listsg[(size_t)tok * 8];
        for (int i = 1; i < ct; ++i) {
            float d = paird[q * 8 + i];
            int c = listsg[(size_t)tok * 8 + i];
            if (d < db || (d == db && c < cb)) { db = d; cb = c; }
        }
        dout[IDX_OFF + tok] = (float)cb;
        loss2[tok] = db;
    }
}

// ---------------- decide (scan): BLOCK per token, full 1024 faithful scan (rare) ----------------
__global__ __launch_bounds__(256) void vq_decide_scan(const float* __restrict__ z,
                                                      const float* __restrict__ emb,
                                                      const float* __restrict__ zsq,
                                                      const float* __restrict__ esq,
                                                      const int* __restrict__ wcnt2,
                                                      const int* __restrict__ wlist2,
                                                      float* __restrict__ loss2,
                                                      float* __restrict__ dout) {
    __shared__ __align__(16) float zrow[DIM];
    __shared__ float dred[256];
    __shared__ int   ired[256];
    int n = wcnt2[0];
    if (n > 4096) n = 4096;
    const int tid = threadIdx.x;
    for (int job = blockIdx.x; job < n; job += 128) {
        int tok = wlist2[job];
        __syncthreads();
        if (tid < 64) ((float4*)zrow)[tid] = ((const float4*)(z + (size_t)tok * DIM))[tid];
        __syncthreads();
        float zq = zsq[tok];
        float a0 = 0.f, a1v = 0.f, a2 = 0.f, a3 = 0.f;
        const float4* e0 = (const float4*)(emb + (size_t)(tid      ) * DIM);
        const float4* e1 = (const float4*)(emb + (size_t)(tid + 256) * DIM);
        const float4* e2 = (const float4*)(emb + (size_t)(tid + 512) * DIM);
        const float4* e3 = (const float4*)(emb + (size_t)(tid + 768) * DIM);
#pragma unroll
        for (int seg = 0; seg < 4; ++seg) {
#pragma unroll
            for (int qq = 0; qq < 16; ++qq) {
                float4 a = ((float4*)zrow)[seg * 16 + qq];
                float4 b0 = e0[seg * 16 + qq], b1 = e1[seg * 16 + qq];
                float4 b2 = e2[seg * 16 + qq], b3 = e3[seg * 16 + qq];
                a0 = fmaf(a.x, b0.x, a0); a0 = fmaf(a.y, b0.y, a0);
                a0 = fmaf(a.z, b0.z, a0); a0 = fmaf(a.w, b0.w, a0);
                a1v = fmaf(a.x, b1.x, a1v); a1v = fmaf(a.y, b1.y, a1v);
                a1v = fmaf(a.z, b1.z, a1v); a1v = fmaf(a.w, b1.w, a1v);
                a2 = fmaf(a.x, b2.x, a2); a2 = fmaf(a.y, b2.y, a2);
                a2 = fmaf(a.z, b2.z, a2); a2 = fmaf(a.w, b2.w, a2);
                a3 = fmaf(a.x, b3.x, a3); a3 = fmaf(a.y, b3.y, a3);
                a3 = fmaf(a.z, b3.z, a3); a3 = fmaf(a.w, b3.w, a3);
            }
        }
        float d0 = (zq + esq[tid      ]) - 2.0f * a0;
        float d1 = (zq + esq[tid + 256]) - 2.0f * a1v;
        float d2 = (zq + esq[tid + 512]) - 2.0f * a2;
        float d3 = (zq + esq[tid + 768]) - 2.0f * a3;
        float db = d0; int cb = tid;
        if (d1 < db) { db = d1; cb = tid + 256; }
        if (d2 < db) { db = d2; cb = tid + 512; }
        if (d3 < db) { db = d3; cb = tid + 768; }
        dred[tid] = db; ired[tid] = cb;
        __syncthreads();
        for (int step = 128; step >= 1; step >>= 1) {
            if (tid < step) {
                float od = dred[tid + step]; int oi = ired[tid + step];
                if (od < dred[tid] || (od == dred[tid] && oi < ired[tid])) {
                    dred[tid] = od; ired[tid] = oi;
                }
            }
            __syncthreads();
        }
        if (tid == 0) {
            dout[IDX_OFF + tok] = (float)ired[0];
            loss2[tok] = dred[0];
        }
    }
}

// ---------------- loss reduction (fixed order) ----------------
__global__ __launch_bounds__(256) void vq_sum(const float* __restrict__ loss2,
                                              float* __restrict__ part) {
    __shared__ float ws[4];
    float s = 0.f;
#pragma unroll
    for (int q = 0; q < 4; ++q)
        s += loss2[blockIdx.x * 1024 + q * 256 + threadIdx.x];
#pragma unroll
    for (int m = 1; m < 64; m <<= 1) s += __shfl_xor(s, m, 64);
    if ((threadIdx.x & 63) == 0) ws[threadIdx.x >> 6] = s;
    __syncthreads();
    if (threadIdx.x == 0) part[blockIdx.x] = ws[0] + ws[1] + ws[2] + ws[3];
}

__global__ __launch_bounds__(64) void vq_final(const float* __restrict__ part,
                                               float* __restrict__ dout) {
    double s = (double)part[threadIdx.x];
#pragma unroll
    for (int m = 1; m < 64; m <<= 1) s += __shfl_xor(s, m, 64);
    if (threadIdx.x == 0) dout[LOSS_OFF] = (float)(s * 1.25 / 16777216.0);
}

// ---------------- gather z_q rows ----------------
__global__ __launch_bounds__(256) void vq_gather(const float* __restrict__ emb,
                                                 float* __restrict__ dout) {
    const int w = threadIdx.x >> 6, l = threadIdx.x & 63;
    for (int tok = blockIdx.x * 4 + w; tok < NTOK; tok += 2048 * 4) {
        int widx = (int)dout[IDX_OFF + tok];
        float4 ev = *(const float4*)&emb[(size_t)widx * DIM + l * 4];
        *(float4*)&dout[(size_t)tok * DIM + l * 4] = ev;
    }
}

extern "C" void kernel_launch(void* const* d_in, const int* in_sizes, int n_in,
                              void* d_out, int out_size, void* d_ws, size_t ws_size,
                              hipStream_t stream) {
    const float* z   = (const float*)d_in[0];
    const float* emb = (const float*)d_in[1];
    float* out = (float*)d_out;

    float* zsq   = out + SC_ZSQ;
    float* loss2 = out + SC_LOSS2;
    float* esq   = out + SC_ESQ;
    float* esqnh = out + SC_ESQNH;
    float* part  = out + SC_PART;
    int*   wcnt  = (int*)(out + SC_WCNT);
    int*   wcnt2 = (int*)(out + SC_WCNT2);
    int*   cntg  = (int*)(out + SC_CNTG);
    int*   listsg= (int*)(out + SC_LISTS);
    int*   wlist = (int*)(out + SC_WLIST);
    int*   wlist2= (int*)(out + SC_WLIST2);
    float* paird = out + SC_PAIRD;
    unsigned short* img  = (unsigned short*)(out + SC_EHIMG);
    unsigned short* zimg = (unsigned short*)(out + SC_ZIMG);

    vq_prep_esq <<<64,   256, 0, stream>>>(emb, esq, esqnh, wcnt, wcnt2);
    vq_prep_z   <<<4096, 256, 0, stream>>>(z, zsq, zimg);
    vq_prep_eimg<<<32,   256, 0, stream>>>(emb, img);
    vq_gemm     <<<1024, 256, 0, stream>>>(zimg, img, esqnh, zsq, wcnt, wlist, cntg, listsg, loss2, out);
    vq_pairs    <<<2048, 256, 0, stream>>>(z, emb, zsq, esq, wcnt, wlist, cntg, listsg, wcnt2, wlist2, paird);
    vq_pick     <<<256,  256, 0, stream>>>(paird, wcnt, wlist, cntg, listsg, loss2, out);
    vq_decide_scan<<<128, 256, 0, stream>>>(z, emb, zsq, esq, wcnt2, wlist2, loss2, out);
    vq_sum      <<<64,   256, 0, stream>>>(loss2, part);
    vq_final    <<<1,    64,  0, stream>>>(part, out);
    vq_gather   <<<2048, 256, 0, stream>>>(emb, out);
}

// Round 16
// 136.783 us; speedup vs baseline: 1.7080x; 1.7080x over previous
//
#include <hip/hip_runtime.h>
#include <hip/hip_bf16.h>

#define NTOK   65536
#define KCODES 1024
#define DIM    256
#define LOSS_OFF ((size_t)NTOK * DIM)
#define IDX_OFF  (LOSS_OFF + 1)

#define MARGA 2e-4f     // a-space margin (validated rounds 8/10/12)

// ---- scratch layout inside the z_q output region (float-slot offsets) ----
#define SC_ZSQ    0              // 65536 f
#define SC_LOSS2  131072         // 65536 f
#define SC_ESQ    196608         // 1024 f
#define SC_ESQNH  197632         // 1024 f
#define SC_PART   198656         // 64 f
#define SC_WCNT   198720         // 1 int
#define SC_WCNT2  198721         // 1 int
#define SC_CNTG   198784         // 65536 int
#define SC_LISTS  264320         // 524288 int (8 per token)
#define SC_WLIST  788608         // 65536 int
#define SC_WLIST2 854144         // 4096 int
#define SC_EHIMG  858240         // 131072 f-slots = 512 KB bf16 emb image
#define SC_ZIMG   989312         // 8388608 f-slots = 32 MB bf16 z image (frag layout)
#define SC_PAIRD  9377920        // 524288 f (per-pair faithful distances)

typedef __attribute__((ext_vector_type(8))) short short8;
typedef __attribute__((ext_vector_type(4))) float f32x4;

__device__ __forceinline__ unsigned f2bf(float x) {
    unsigned u = __float_as_uint(x);
    return (u + 0x7FFFu + ((u >> 16) & 1u)) >> 16;   // RNE
}

__device__ __forceinline__ void gload16(const void* g, void* l) {
    __builtin_amdgcn_global_load_lds((const __attribute__((address_space(1))) unsigned int*)g,
                                     (__attribute__((address_space(3))) unsigned int*)l,
                                     16, 0, 0);
}

// faithful fp32 distance (validated rounds 4-12): sequential single-acc FMA chain
__device__ __forceinline__ float faithful_d(const float* __restrict__ z,
                                            const float* __restrict__ emb,
                                            float zsq, float esq, int tok, int c) {
    const float4* zr = (const float4*)(z + (size_t)tok * DIM);
    const float4* er = (const float4*)(emb + (size_t)c * DIM);
    float acc = 0.f;
#pragma unroll 8
    for (int q = 0; q < 64; ++q) {
        float4 a = zr[q], b = er[q];
        acc = fmaf(a.x, b.x, acc); acc = fmaf(a.y, b.y, acc);
        acc = fmaf(a.z, b.z, acc); acc = fmaf(a.w, b.w, acc);
    }
    float t1 = zsq + esq;
    return t1 - 2.0f * acc;
}

// wave-parallel numpy pairwise sum-of-squares replica (16 lanes per 256-row)
__device__ __forceinline__ float np_rowsq256_wave(const float* row, int sub) {
    const int j = sub & 7, half = sub >> 3;
    const float* a = row + half * 128 + j;
    float r = 0.f;
#pragma unroll
    for (int i = 0; i < 16; ++i) {
        float v = a[i * 8];
        float sq = v * v;
        asm volatile("" : "+v"(sq));
        r += sq;
    }
    float t = r + __shfl_xor(r, 1, 64);
    t = t + __shfl_xor(t, 2, 64);
    t = t + __shfl_xor(t, 4, 64);
    t = t + __shfl_xor(t, 8, 64);
    return t;
}

// ---------------- prep: esq / esqnh (+ worklist counters reset) ----------------
__global__ __launch_bounds__(256) void vq_prep_esq(const float* __restrict__ emb,
                                                   float* __restrict__ esq,
                                                   float* __restrict__ esqnh,
                                                   int* __restrict__ wcnt,
                                                   int* __restrict__ wcnt2) {
    if (blockIdx.x == 0 && threadIdx.x == 0) { *wcnt = 0; *wcnt2 = 0; }
    int code = blockIdx.x * 16 + (threadIdx.x >> 4);   // grid 64
    int sub = threadIdx.x & 15;
    float tot = np_rowsq256_wave(emb + (size_t)code * DIM, sub);
    if (sub == 0) { esq[code] = tot; esqnh[code] = -0.5f * tot; }
}

// ---------------- prep: zsq (np-faithful) + bf16 z image in MFMA-fragment layout ----------------
__global__ __launch_bounds__(256) void vq_prep_z(const float* __restrict__ z,
                                                 float* __restrict__ zsq,
                                                 unsigned short* __restrict__ zimg) {
    int tok = blockIdx.x * 16 + (threadIdx.x >> 4);    // grid 4096
    int sub = threadIdx.x & 15;
    float tot = np_rowsq256_wave(z + (size_t)tok * DIM, sub);
    if (sub == 0) zsq[tok] = tot;

    const float* src = z + (size_t)tok * DIM + sub * 16;
    float4 v0 = *(const float4*)&src[0],  v1 = *(const float4*)&src[4];
    float4 v2 = *(const float4*)&src[8],  v3 = *(const float4*)&src[12];
    uint4 p0, p1;
    p0.x = f2bf(v0.x) | (f2bf(v0.y) << 16);  p0.y = f2bf(v0.z) | (f2bf(v0.w) << 16);
    p0.z = f2bf(v1.x) | (f2bf(v1.y) << 16);  p0.w = f2bf(v1.z) | (f2bf(v1.w) << 16);
    p1.x = f2bf(v2.x) | (f2bf(v2.y) << 16);  p1.y = f2bf(v2.z) | (f2bf(v2.w) << 16);
    p1.z = f2bf(v3.x) | (f2bf(v3.y) << 16);  p1.w = f2bf(v3.z) | (f2bf(v3.w) << 16);

    int bid = tok >> 6, tf = (tok >> 4) & 3, sl = tok & 15;
    int g0 = sub * 2, g1 = g0 + 1;
    size_t rowbase = ((size_t)bid * 4 + tf) * 8;
    char* d0 = (char*)zimg + ((rowbase + (g0 >> 2)) << 10) + (((g0 & 3) * 16 + sl) << 4);
    char* d1 = (char*)zimg + ((rowbase + (g1 >> 2)) << 10) + (((g1 & 3) * 16 + sl) << 4);
    *(uint4*)d0 = p0;
    *(uint4*)d1 = p1;
}

// ---------------- prep: bf16 emb image in pre-swizzled LDS slice layout ----------------
__global__ __launch_bounds__(256) void vq_prep_eimg(const float* __restrict__ emb,
                                                    unsigned short* __restrict__ img) {
    int job = blockIdx.x * 256 + threadIdx.x;   // grid 32
    int code = job >> 3, ks = job & 7;
    int cc = (code >> 6) & 3, lcl = (code >> 8) * 64 + (code & 63);
    const float* src = emb + (size_t)code * DIM + ks * 32;
    char* base = (char*)img + (size_t)(cc * 8 + ks) * 16384;
#pragma unroll
    for (int q = 0; q < 4; ++q) {
        float4 v0 = *(const float4*)&src[q * 8];
        float4 v1 = *(const float4*)&src[q * 8 + 4];
        uint4 p;
        p.x = f2bf(v0.x) | (f2bf(v0.y) << 16);
        p.y = f2bf(v0.z) | (f2bf(v0.w) << 16);
        p.z = f2bf(v1.x) | (f2bf(v1.y) << 16);
        p.w = f2bf(v1.z) | (f2bf(v1.w) << 16);
        *(uint4*)(base + lcl * 64 + ((q * 16) ^ (((lcl >> 1) & 3) << 4))) = p;
    }
}

// ---------------- SINGLE-PASS GEMM filter, GLOBAL running-max threshold ----------------
// Per c-tile fold: each wave publishes its per-token tile max to LDS; all waves merge
// -> m_run becomes the BLOCK-global running max (fix for round-15's per-wave flood).
// Superset: m_run <= a1_final throughout, so every code with a >= a1_final - MARGA is
// enumerated at its tile. At loop end m_run == a1_final on every wave.
__global__ __launch_bounds__(256, 2) void vq_gemm(const unsigned short* __restrict__ zimg,
                                                  const unsigned short* __restrict__ img,
                                                  const float* __restrict__ esqnh,
                                                  const float* __restrict__ zsq,
                                                  int* __restrict__ wcnt,
                                                  int* __restrict__ wlist,
                                                  int* __restrict__ cntg,
                                                  int* __restrict__ listsg,
                                                  float* __restrict__ loss2,
                                                  float* __restrict__ dout) {
    __shared__ __align__(16) short eh_s[2][8192];     // 2 x 16 KB (async-staged e image)
    __shared__ float a1w_s[4][64];                    // per-wave per-token tile maxes
    __shared__ int   cnt_s[64];
    __shared__ int   lists_s[64 * 16];                // speculative codes (4 KB)
    __shared__ float avals_s[64 * 16];                // their a-values (4 KB)

    const int tid = threadIdx.x, bid = blockIdx.x;
    const int w = tid >> 6, l = tid & 63;
    const int t0 = bid * 64;

    // z fragments -> registers (coalesced 1KB wave loads; layout validated rounds 11/12)
    short8 zf[4][8];
#pragma unroll
    for (int tf = 0; tf < 4; ++tf)
#pragma unroll
        for (int ks = 0; ks < 8; ++ks)
            zf[tf][ks] = *(const short8*)((const char*)zimg +
                           ((((size_t)bid * 4 + tf) * 8 + ks) << 10) + (size_t)l * 16);

    if (tid < 64) cnt_s[tid] = 0;
    // issue eh slice 0 (async -> eh_s[0])
    {
        const char* gs = (const char*)img + w * 4096 + (size_t)l * 16;
        char* ld = (char*)&eh_s[0][0] + w * 4096;
#pragma unroll
        for (int i = 0; i < 4; ++i) gload16(gs + i * 1024, ld + i * 1024);
    }
    __syncthreads();

    float m_run[4] = {-3.4e38f, -3.4e38f, -3.4e38f, -3.4e38f};
    f32x4 acc[4][4];

#pragma unroll
    for (int c = 0; c < 4; ++c) {
#pragma unroll
        for (int f = 0; f < 4; ++f) {
            f32x4 e4 = *(const f32x4*)&esqnh[w * 256 + c * 64 + f * 16 + (l >> 4) * 4];
#pragma unroll
            for (int tf = 0; tf < 4; ++tf) acc[f][tf] = e4;
        }
#pragma unroll
        for (int ks = 0; ks < 8; ++ks) {
            int s = c * 8 + ks, buf = s & 1;
            if (s < 31) {   // prefetch next slice async into other buffer
                const char* gs = (const char*)img + (size_t)(s + 1) * 16384 + w * 4096 + (size_t)l * 16;
                char* ld = (char*)&eh_s[buf ^ 1][0] + w * 4096;
#pragma unroll
                for (int i = 0; i < 4; ++i) gload16(gs + i * 1024, ld + i * 1024);
            }
            short8 afr[4];
#pragma unroll
            for (int f = 0; f < 4; ++f) {
                int lcl = w * 64 + f * 16 + (l & 15);
                int byte = lcl * 64 + (((l >> 4) * 16) ^ (((lcl >> 1) & 3) << 4));
                afr[f] = *(const short8*)((const char*)&eh_s[buf][0] + byte);
            }
#pragma unroll
            for (int f = 0; f < 4; ++f)
#pragma unroll
                for (int tf = 0; tf < 4; ++tf)
                    acc[f][tf] = __builtin_amdgcn_mfma_f32_16x16x32_bf16(
                        afr[f], zf[tf][ks], acc[f][tf], 0, 0, 0);
            __syncthreads();   // validated round-12 schedule (drains prefetch; no spill)
        }
        // fold step 1: per-wave per-token tile max -> LDS
#pragma unroll
        for (int tf = 0; tf < 4; ++tf) {
            float m0 = fmaxf(fmaxf(acc[0][tf][0], acc[0][tf][1]), fmaxf(acc[0][tf][2], acc[0][tf][3]));
            float m1 = fmaxf(fmaxf(acc[1][tf][0], acc[1][tf][1]), fmaxf(acc[1][tf][2], acc[1][tf][3]));
            float m2 = fmaxf(fmaxf(acc[2][tf][0], acc[2][tf][1]), fmaxf(acc[2][tf][2], acc[2][tf][3]));
            float m3 = fmaxf(fmaxf(acc[3][tf][0], acc[3][tf][1]), fmaxf(acc[3][tf][2], acc[3][tf][3]));
            float tm = fmaxf(fmaxf(m0, m1), fmaxf(m2, m3));
            tm = fmaxf(tm, __shfl_xor(tm, 16, 64));
            tm = fmaxf(tm, __shfl_xor(tm, 32, 64));   // all lanes of same (l&15) hold tm
            if (l < 16) a1w_s[w][tf * 16 + l] = tm;
        }
        __syncthreads();
        // fold step 2: merge to block-global running max, then enumerate
#pragma unroll
        for (int tf = 0; tf < 4; ++tf) {
            int tokl = tf * 16 + (l & 15);
            float gm = fmaxf(fmaxf(a1w_s[0][tokl], a1w_s[1][tokl]),
                             fmaxf(a1w_s[2][tokl], a1w_s[3][tokl]));
            m_run[tf] = fmaxf(m_run[tf], gm);
            float thr = m_run[tf] - MARGA;
#pragma unroll
            for (int f = 0; f < 4; ++f)
#pragma unroll
                for (int r = 0; r < 4; ++r) {
                    float a = acc[f][tf][r];
                    if (a >= thr) {
                        int code = w * 256 + c * 64 + f * 16 + (l >> 4) * 4 + r;
                        int pos = atomicAdd(&cnt_s[tokl], 1);
                        if (pos < 16) {
                            lists_s[tokl * 16 + pos] = code;
                            avals_s[tokl * 16 + pos] = a;
                        }
                    }
                }
        }
        // (next a1w_s write is after 8 K-step barriers of the next tile -> no race)
    }

    __syncthreads();   // lists_s/avals_s visible to epilogue

    // epilogue: m_run == a1_final on every wave; tid<64 (wave 0) finalizes its tokens
    if (tid < 64) {
        int t = t0 + tid;
        int tfsel = tid >> 4;
        float a1v = (tfsel == 0) ? m_run[0] : (tfsel == 1) ? m_run[1]
                  : (tfsel == 2) ? m_run[2] : m_run[3];
        int ct_raw = cnt_s[tid];
        if (ct_raw > 16) {              // list overflow -> exact full scan path
            int pos = atomicAdd(wcnt, 1);
            wlist[pos] = t;
            cntg[t] = 999;
        } else {
            float thr = a1v - MARGA;
            int kept = 0, first = 0;
            for (int i = 0; i < ct_raw; ++i) {
                float av = avals_s[tid * 16 + i];
                if (av >= thr) {
                    int code = lists_s[tid * 16 + i];
                    if (kept == 0) first = code;
                    if (kept < 8) listsg[(size_t)t * 8 + kept] = code;
                    ++kept;
                }
            }
            if (kept == 1) {
                dout[IDX_OFF + t] = (float)first;
                loss2[t] = fmaf(-2.f, a1v, zsq[t]);
            } else {
                int pos = atomicAdd(wcnt, 1);
                wlist[pos] = t;
                cntg[t] = (kept > 8) ? 999 : kept;
            }
        }
    }
}

// ---------------- pairs: one LANE per (hard-token, candidate) pair ----------------
__global__ __launch_bounds__(256) void vq_pairs(const float* __restrict__ z,
                                                const float* __restrict__ emb,
                                                const float* __restrict__ zsq,
                                                const float* __restrict__ esq,
                                                const int* __restrict__ wcnt,
                                                const int* __restrict__ wlist,
                                                const int* __restrict__ cntg,
                                                const int* __restrict__ listsg,
                                                int* __restrict__ wcnt2,
                                                int* __restrict__ wlist2,
                                                float* __restrict__ paird) {
    const int n = wcnt[0];
    const int total = 8 * n;
    for (int p = blockIdx.x * 256 + threadIdx.x; p < total; p += 2048 * 256) {
        int q = p >> 3, slot = p & 7;
        int tok = wlist[q];
        int ct = cntg[tok];
        if (ct == 0 || ct > 8) {
            if (slot == 0) {
                int pos = atomicAdd(wcnt2, 1);
                if (pos < 4096) wlist2[pos] = tok;
            }
            continue;
        }
        if (slot >= ct) continue;
        int code = listsg[(size_t)tok * 8 + slot];
        paird[p] = faithful_d(z, emb, zsq[tok], esq[code], tok, code);
    }
}

// ---------------- pick: thread per hard token, lexicographic (d, code) argmin ----------------
__global__ __launch_bounds__(256) void vq_pick(const float* __restrict__ paird,
                                               const int* __restrict__ wcnt,
                                               const int* __restrict__ wlist,
                                               const int* __restrict__ cntg,
                                               const int* __restrict__ listsg,
                                               float* __restrict__ loss2,
                                               float* __restrict__ dout) {
    const int n = wcnt[0];
    for (int q = blockIdx.x * 256 + threadIdx.x; q < n; q += 256 * 256) {
        int tok = wlist[q];
        int ct = cntg[tok];
        if (ct == 0 || ct > 8) continue;   // scan kernel owns these
        float db = paird[q * 8];
        int cb = listsg[(size_t)tok * 8];
        for (int i = 1; i < ct; ++i) {
            float d = paird[q * 8 + i];
            int c = listsg[(size_t)tok * 8 + i];
            if (d < db || (d == db && c < cb)) { db = d; cb = c; }
        }
        dout[IDX_OFF + tok] = (float)cb;
        loss2[tok] = db;
    }
}

// ---------------- decide (scan): BLOCK per token, full 1024 faithful scan (rare) ----------------
__global__ __launch_bounds__(256) void vq_decide_scan(const float* __restrict__ z,
                                                      const float* __restrict__ emb,
                                                      const float* __restrict__ zsq,
                                                      const float* __restrict__ esq,
                                                      const int* __restrict__ wcnt2,
                                                      const int* __restrict__ wlist2,
                                                      float* __restrict__ loss2,
                                                      float* __restrict__ dout) {
    __shared__ __align__(16) float zrow[DIM];
    __shared__ float dred[256];
    __shared__ int   ired[256];
    int n = wcnt2[0];
    if (n > 4096) n = 4096;
    const int tid = threadIdx.x;
    for (int job = blockIdx.x; job < n; job += 128) {
        int tok = wlist2[job];
        __syncthreads();
        if (tid < 64) ((float4*)zrow)[tid] = ((const float4*)(z + (size_t)tok * DIM))[tid];
        __syncthreads();
        float zq = zsq[tok];
        float a0 = 0.f, a1v = 0.f, a2 = 0.f, a3 = 0.f;
        const float4* e0 = (const float4*)(emb + (size_t)(tid      ) * DIM);
        const float4* e1 = (const float4*)(emb + (size_t)(tid + 256) * DIM);
        const float4* e2 = (const float4*)(emb + (size_t)(tid + 512) * DIM);
        const float4* e3 = (const float4*)(emb + (size_t)(tid + 768) * DIM);
#pragma unroll
        for (int seg = 0; seg < 4; ++seg) {
#pragma unroll
            for (int qq = 0; qq < 16; ++qq) {
                float4 a = ((float4*)zrow)[seg * 16 + qq];
                float4 b0 = e0[seg * 16 + qq], b1 = e1[seg * 16 + qq];
                float4 b2 = e2[seg * 16 + qq], b3 = e3[seg * 16 + qq];
                a0 = fmaf(a.x, b0.x, a0); a0 = fmaf(a.y, b0.y, a0);
                a0 = fmaf(a.z, b0.z, a0); a0 = fmaf(a.w, b0.w, a0);
                a1v = fmaf(a.x, b1.x, a1v); a1v = fmaf(a.y, b1.y, a1v);
                a1v = fmaf(a.z, b1.z, a1v); a1v = fmaf(a.w, b1.w, a1v);
                a2 = fmaf(a.x, b2.x, a2); a2 = fmaf(a.y, b2.y, a2);
                a2 = fmaf(a.z, b2.z, a2); a2 = fmaf(a.w, b2.w, a2);
                a3 = fmaf(a.x, b3.x, a3); a3 = fmaf(a.y, b3.y, a3);
                a3 = fmaf(a.z, b3.z, a3); a3 = fmaf(a.w, b3.w, a3);
            }
        }
        float d0 = (zq + esq[tid      ]) - 2.0f * a0;
        float d1 = (zq + esq[tid + 256]) - 2.0f * a1v;
        float d2 = (zq + esq[tid + 512]) - 2.0f * a2;
        float d3 = (zq + esq[tid + 768]) - 2.0f * a3;
        float db = d0; int cb = tid;
        if (d1 < db) { db = d1; cb = tid + 256; }
        if (d2 < db) { db = d2; cb = tid + 512; }
        if (d3 < db) { db = d3; cb = tid + 768; }
        dred[tid] = db; ired[tid] = cb;
        __syncthreads();
        for (int step = 128; step >= 1; step >>= 1) {
            if (tid < step) {
                float od = dred[tid + step]; int oi = ired[tid + step];
                if (od < dred[tid] || (od == dred[tid] && oi < ired[tid])) {
                    dred[tid] = od; ired[tid] = oi;
                }
            }
            __syncthreads();
        }
        if (tid == 0) {
            dout[IDX_OFF + tok] = (float)ired[0];
            loss2[tok] = dred[0];
        }
    }
}

// ---------------- loss reduction (fixed order) ----------------
__global__ __launch_bounds__(256) void vq_sum(const float* __restrict__ loss2,
                                              float* __restrict__ part) {
    __shared__ float ws[4];
    float s = 0.f;
#pragma unroll
    for (int q = 0; q < 4; ++q)
        s += loss2[blockIdx.x * 1024 + q * 256 + threadIdx.x];
#pragma unroll
    for (int m = 1; m < 64; m <<= 1) s += __shfl_xor(s, m, 64);
    if ((threadIdx.x & 63) == 0) ws[threadIdx.x >> 6] = s;
    __syncthreads();
    if (threadIdx.x == 0) part[blockIdx.x] = ws[0] + ws[1] + ws[2] + ws[3];
}

__global__ __launch_bounds__(64) void vq_final(const float* __restrict__ part,
                                               float* __restrict__ dout) {
    double s = (double)part[threadIdx.x];
#pragma unroll
    for (int m = 1; m < 64; m <<= 1) s += __shfl_xor(s, m, 64);
    if (threadIdx.x == 0) dout[LOSS_OFF] = (float)(s * 1.25 / 16777216.0);
}

// ---------------- gather z_q rows ----------------
__global__ __launch_bounds__(256) void vq_gather(const float* __restrict__ emb,
                                                 float* __restrict__ dout) {
    const int w = threadIdx.x >> 6, l = threadIdx.x & 63;
    for (int tok = blockIdx.x * 4 + w; tok < NTOK; tok += 2048 * 4) {
        int widx = (int)dout[IDX_OFF + tok];
        float4 ev = *(const float4*)&emb[(size_t)widx * DIM + l * 4];
        *(float4*)&dout[(size_t)tok * DIM + l * 4] = ev;
    }
}

extern "C" void kernel_launch(void* const* d_in, const int* in_sizes, int n_in,
                              void* d_out, int out_size, void* d_ws, size_t ws_size,
                              hipStream_t stream) {
    const float* z   = (const float*)d_in[0];
    const float* emb = (const float*)d_in[1];
    float* out = (float*)d_out;

    float* zsq   = out + SC_ZSQ;
    float* loss2 = out + SC_LOSS2;
    float* esq   = out + SC_ESQ;
    float* esqnh = out + SC_ESQNH;
    float* part  = out + SC_PART;
    int*   wcnt  = (int*)(out + SC_WCNT);
    int*   wcnt2 = (int*)(out + SC_WCNT2);
    int*   cntg  = (int*)(out + SC_CNTG);
    int*   listsg= (int*)(out + SC_LISTS);
    int*   wlist = (int*)(out + SC_WLIST);
    int*   wlist2= (int*)(out + SC_WLIST2);
    float* paird = out + SC_PAIRD;
    unsigned short* img  = (unsigned short*)(out + SC_EHIMG);
    unsigned short* zimg = (unsigned short*)(out + SC_ZIMG);

    vq_prep_esq <<<64,   256, 0, stream>>>(emb, esq, esqnh, wcnt, wcnt2);
    vq_prep_z   <<<4096, 256, 0, stream>>>(z, zsq, zimg);
    vq_prep_eimg<<<32,   256, 0, stream>>>(emb, img);
    vq_gemm     <<<1024, 256, 0, stream>>>(zimg, img, esqnh, zsq, wcnt, wlist, cntg, listsg, loss2, out);
    vq_pairs    <<<2048, 256, 0, stream>>>(z, emb, zsq, esq, wcnt, wlist, cntg, listsg, wcnt2, wlist2, paird);
    vq_pick     <<<256,  256, 0, stream>>>(paird, wcnt, wlist, cntg, listsg, loss2, out);
    vq_decide_scan<<<128, 256, 0, stream>>>(z, emb, zsq, esq, wcnt2, wlist2, loss2, out);
    vq_sum      <<<64,   256, 0, stream>>>(loss2, part);
    vq_final    <<<1,    64,  0, stream>>>(part, out);
    vq_gather   <<<2048, 256, 0, stream>>>(emb, out);
}

// Round 18
// 128.790 us; speedup vs baseline: 1.8140x; 1.0621x over previous
//
#include <hip/hip_runtime.h>
#include <hip/hip_bf16.h>

#define NTOK   65536
#define KCODES 1024
#define DIM    256
#define LOSS_OFF ((size_t)NTOK * DIM)
#define IDX_OFF  (LOSS_OFF + 1)

#define MARGA 2e-4f     // a-space margin (validated rounds 8/10/12/16)

// ---- scratch layout inside the z_q output region (float-slot offsets) ----
#define SC_ZSQ    0              // 65536 f
#define SC_LOSS2  131072         // 65536 f
#define SC_ESQ    196608         // 1024 f
#define SC_ESQNH  197632         // 1024 f
#define SC_PART   198656         // 64 f
#define SC_WCNT   198720         // 1 int
#define SC_WCNT2  198721         // 1 int
#define SC_CNTG   198784         // 65536 int
#define SC_LISTS  264320         // 524288 int (8 per token)
#define SC_WLIST  788608         // 65536 int
#define SC_WLIST2 854144         // 4096 int
#define SC_EHIMG  858240         // 131072 f-slots = 512 KB bf16 emb image
#define SC_ZIMG   989312         // 8388608 f-slots = 32 MB bf16 z image (frag layout)
#define SC_PAIRD  9377920        // 524288 f (per-pair faithful distances)

typedef __attribute__((ext_vector_type(8))) short short8;
typedef __attribute__((ext_vector_type(4))) float f32x4;

__device__ __forceinline__ unsigned f2bf(float x) {
    unsigned u = __float_as_uint(x);
    return (u + 0x7FFFu + ((u >> 16) & 1u)) >> 16;   // RNE
}

__device__ __forceinline__ void gload16(const void* g, void* l) {
    __builtin_amdgcn_global_load_lds((const __attribute__((address_space(1))) unsigned int*)g,
                                     (__attribute__((address_space(3))) unsigned int*)l,
                                     16, 0, 0);
}

// faithful fp32 distance (validated rounds 4-16): sequential single-acc FMA chain
__device__ __forceinline__ float faithful_d(const float* __restrict__ z,
                                            const float* __restrict__ emb,
                                            float zsq, float esq, int tok, int c) {
    const float4* zr = (const float4*)(z + (size_t)tok * DIM);
    const float4* er = (const float4*)(emb + (size_t)c * DIM);
    float acc = 0.f;
#pragma unroll 8
    for (int q = 0; q < 64; ++q) {
        float4 a = zr[q], b = er[q];
        acc = fmaf(a.x, b.x, acc); acc = fmaf(a.y, b.y, acc);
        acc = fmaf(a.z, b.z, acc); acc = fmaf(a.w, b.w, acc);
    }
    float t1 = zsq + esq;
    return t1 - 2.0f * acc;
}

// wave-parallel numpy pairwise sum-of-squares replica (16 lanes per 256-row)
__device__ __forceinline__ float np_rowsq256_wave(const float* row, int sub) {
    const int j = sub & 7, half = sub >> 3;
    const float* a = row + half * 128 + j;
    float r = 0.f;
#pragma unroll
    for (int i = 0; i < 16; ++i) {
        float v = a[i * 8];
        float sq = v * v;
        asm volatile("" : "+v"(sq));
        r += sq;
    }
    float t = r + __shfl_xor(r, 1, 64);
    t = t + __shfl_xor(t, 2, 64);
    t = t + __shfl_xor(t, 4, 64);
    t = t + __shfl_xor(t, 8, 64);
    return t;
}

// ---------------- prep: esq/esqnh + bf16 emb image (merged; + counter reset) ----------------
__global__ __launch_bounds__(256) void vq_prep_emb(const float* __restrict__ emb,
                                                   float* __restrict__ esq,
                                                   float* __restrict__ esqnh,
                                                   unsigned short* __restrict__ img,
                                                   int* __restrict__ wcnt,
                                                   int* __restrict__ wcnt2) {
    if (blockIdx.x == 0 && threadIdx.x == 0) { *wcnt = 0; *wcnt2 = 0; }
    // part A: np-faithful esq, 16 codes per block (grid 64)
    {
        int code = blockIdx.x * 16 + (threadIdx.x >> 4);
        int sub = threadIdx.x & 15;
        float tot = np_rowsq256_wave(emb + (size_t)code * DIM, sub);
        if (sub == 0) { esq[code] = tot; esqnh[code] = -0.5f * tot; }
    }
    // part B: eimg, 128 (code,ks) jobs per block
    if (threadIdx.x < 128) {
        int job = blockIdx.x * 128 + threadIdx.x;   // 8192 jobs
        int code = job >> 3, ks = job & 7;
        int cc = (code >> 6) & 3, lcl = (code >> 8) * 64 + (code & 63);
        const float* src = emb + (size_t)code * DIM + ks * 32;
        char* base = (char*)img + (size_t)(cc * 8 + ks) * 16384;
#pragma unroll
        for (int q = 0; q < 4; ++q) {
            float4 v0 = *(const float4*)&src[q * 8];
            float4 v1 = *(const float4*)&src[q * 8 + 4];
            uint4 p;
            p.x = f2bf(v0.x) | (f2bf(v0.y) << 16);
            p.y = f2bf(v0.z) | (f2bf(v0.w) << 16);
            p.z = f2bf(v1.x) | (f2bf(v1.y) << 16);
            p.w = f2bf(v1.z) | (f2bf(v1.w) << 16);
            *(uint4*)(base + lcl * 64 + ((q * 16) ^ (((lcl >> 1) & 3) << 4))) = p;
        }
    }
}

// ---------------- prep: zsq (np-faithful) + bf16 z image in MFMA-fragment layout ----------------
__global__ __launch_bounds__(256) void vq_prep_z(const float* __restrict__ z,
                                                 float* __restrict__ zsq,
                                                 unsigned short* __restrict__ zimg) {
    int tok = blockIdx.x * 16 + (threadIdx.x >> 4);    // grid 4096
    int sub = threadIdx.x & 15;
    float tot = np_rowsq256_wave(z + (size_t)tok * DIM, sub);
    if (sub == 0) zsq[tok] = tot;

    const float* src = z + (size_t)tok * DIM + sub * 16;
    float4 v0 = *(const float4*)&src[0],  v1 = *(const float4*)&src[4];
    float4 v2 = *(const float4*)&src[8],  v3 = *(const float4*)&src[12];
    uint4 p0, p1;
    p0.x = f2bf(v0.x) | (f2bf(v0.y) << 16);  p0.y = f2bf(v0.z) | (f2bf(v0.w) << 16);
    p0.z = f2bf(v1.x) | (f2bf(v1.y) << 16);  p0.w = f2bf(v1.z) | (f2bf(v1.w) << 16);
    p1.x = f2bf(v2.x) | (f2bf(v2.y) << 16);  p1.y = f2bf(v2.z) | (f2bf(v2.w) << 16);
    p1.z = f2bf(v3.x) | (f2bf(v3.y) << 16);  p1.w = f2bf(v3.z) | (f2bf(v3.w) << 16);

    int bid = tok >> 6, tf = (tok >> 4) & 3, sl = tok & 15;
    int g0 = sub * 2, g1 = g0 + 1;
    size_t rowbase = ((size_t)bid * 4 + tf) * 8;
    char* d0 = (char*)zimg + ((rowbase + (g0 >> 2)) << 10) + (((g0 & 3) * 16 + sl) << 4);
    char* d1 = (char*)zimg + ((rowbase + (g1 >> 2)) << 10) + (((g1 & 3) * 16 + sl) << 4);
    *(uint4*)d0 = p0;
    *(uint4*)d1 = p1;
}

// ---------------- SINGLE-PASS GEMM filter, K-chunk 64 (2 slices/phase) ----------------
// 16 phases instead of 32 K-steps: per phase stage 32 KB (2 slices), ONE barrier,
// 32 MFMAs. Round-17 bug fixed: slice B lives at byte +16384 within each buffer
// (was +8192 -> wave 0 slice-B DMA collided with wave 2 slice-A -> absmax 1019).
__global__ __launch_bounds__(256, 2) void vq_gemm(const unsigned short* __restrict__ zimg,
                                                  const unsigned short* __restrict__ img,
                                                  const float* __restrict__ esqnh,
                                                  const float* __restrict__ zsq,
                                                  int* __restrict__ wcnt,
                                                  int* __restrict__ wlist,
                                                  int* __restrict__ cntg,
                                                  int* __restrict__ listsg,
                                                  float* __restrict__ loss2,
                                                  float* __restrict__ dout) {
    __shared__ __align__(16) short eh_s[2][16384];    // 2 x 32 KB (2 x 16 KB slices each)
    __shared__ float a1w_s[4][64];                    // per-wave per-token tile maxes
    __shared__ int   cnt_s[64];
    __shared__ int   lists_s[64 * 16];                // speculative codes (4 KB)
    __shared__ float avals_s[64 * 16];                // their a-values (4 KB)

    const int tid = threadIdx.x, bid = blockIdx.x;
    const int w = tid >> 6, l = tid & 63;
    const int t0 = bid * 64;

    // z fragments -> registers (coalesced 1KB wave loads; layout validated rounds 11-16)
    short8 zf[4][8];
#pragma unroll
    for (int tf = 0; tf < 4; ++tf)
#pragma unroll
        for (int ks = 0; ks < 8; ++ks)
            zf[tf][ks] = *(const short8*)((const char*)zimg +
                           ((((size_t)bid * 4 + tf) * 8 + ks) << 10) + (size_t)l * 16);

    if (tid < 64) cnt_s[tid] = 0;
    // prologue: stage phase 0 (slices 0,1) into eh_s[0]; slice B at +16384 bytes
    {
        const char* gs = (const char*)img + w * 4096 + (size_t)l * 16;
        char* ld = (char*)&eh_s[0][0] + w * 4096;
#pragma unroll
        for (int i = 0; i < 4; ++i) gload16(gs + i * 1024, ld + i * 1024);
        const char* gs1 = gs + 16384;
        char* ld1 = ld + 16384;
#pragma unroll
        for (int i = 0; i < 4; ++i) gload16(gs1 + i * 1024, ld1 + i * 1024);
    }
    __syncthreads();

    float m_run[4] = {-3.4e38f, -3.4e38f, -3.4e38f, -3.4e38f};
    f32x4 acc[4][4];

#pragma unroll
    for (int p = 0; p < 16; ++p) {                    // phase = 2 K-steps (K-chunk 64)
        const int c = p >> 2, q = p & 3, buf = p & 1;
        if (q == 0) {
#pragma unroll
            for (int f = 0; f < 4; ++f) {
                f32x4 e4 = *(const f32x4*)&esqnh[w * 256 + c * 64 + f * 16 + (l >> 4) * 4];
#pragma unroll
                for (int tf = 0; tf < 4; ++tf) acc[f][tf] = e4;
            }
        }
        if (p < 15) {   // prefetch next phase's 2 slices into other buffer
            const char* gs = (const char*)img + (size_t)(p + 1) * 32768 + w * 4096 + (size_t)l * 16;
            char* ld = (char*)&eh_s[buf ^ 1][0] + w * 4096;
#pragma unroll
            for (int i = 0; i < 4; ++i) gload16(gs + i * 1024, ld + i * 1024);
            const char* gs1 = gs + 16384;
            char* ld1 = ld + 16384;
#pragma unroll
            for (int i = 0; i < 4; ++i) gload16(gs1 + i * 1024, ld1 + i * 1024);
        }
        // half-phase 0 (K-step 2p -> zf ks = 2q; slice A at byte 0)
        {
            short8 afr[4];
#pragma unroll
            for (int f = 0; f < 4; ++f) {
                int lcl = w * 64 + f * 16 + (l & 15);
                int byte = lcl * 64 + (((l >> 4) * 16) ^ (((lcl >> 1) & 3) << 4));
                afr[f] = *(const short8*)((const char*)&eh_s[buf][0] + byte);
            }
#pragma unroll
            for (int f = 0; f < 4; ++f)
#pragma unroll
                for (int tf = 0; tf < 4; ++tf)
                    acc[f][tf] = __builtin_amdgcn_mfma_f32_16x16x32_bf16(
                        afr[f], zf[tf][2 * q], acc[f][tf], 0, 0, 0);
        }
        // half-phase 1 (K-step 2p+1 -> zf ks = 2q+1; slice B at byte +16384)
        {
            short8 afr[4];
#pragma unroll
            for (int f = 0; f < 4; ++f) {
                int lcl = w * 64 + f * 16 + (l & 15);
                int byte = 16384 + lcl * 64 + (((l >> 4) * 16) ^ (((lcl >> 1) & 3) << 4));
                afr[f] = *(const short8*)((const char*)&eh_s[buf][0] + byte);
            }
#pragma unroll
            for (int f = 0; f < 4; ++f)
#pragma unroll
                for (int tf = 0; tf < 4; ++tf)
                    acc[f][tf] = __builtin_amdgcn_mfma_f32_16x16x32_bf16(
                        afr[f], zf[tf][2 * q + 1], acc[f][tf], 0, 0, 0);
        }
        __syncthreads();   // drains prefetch + buffer swap (one barrier per 2 K-steps)

        if (q == 3) {      // end of c-tile: fold (byte-identical to round 16)
            // fold step 1: per-wave per-token tile max -> LDS
#pragma unroll
            for (int tf = 0; tf < 4; ++tf) {
                float m0 = fmaxf(fmaxf(acc[0][tf][0], acc[0][tf][1]), fmaxf(acc[0][tf][2], acc[0][tf][3]));
                float m1 = fmaxf(fmaxf(acc[1][tf][0], acc[1][tf][1]), fmaxf(acc[1][tf][2], acc[1][tf][3]));
                float m2 = fmaxf(fmaxf(acc[2][tf][0], acc[2][tf][1]), fmaxf(acc[2][tf][2], acc[2][tf][3]));
                float m3 = fmaxf(fmaxf(acc[3][tf][0], acc[3][tf][1]), fmaxf(acc[3][tf][2], acc[3][tf][3]));
                float tm = fmaxf(fmaxf(m0, m1), fmaxf(m2, m3));
                tm = fmaxf(tm, __shfl_xor(tm, 16, 64));
                tm = fmaxf(tm, __shfl_xor(tm, 32, 64));
                if (l < 16) a1w_s[w][tf * 16 + l] = tm;
            }
            __syncthreads();
            // fold step 2: merge to block-global running max, then enumerate
#pragma unroll
            for (int tf = 0; tf < 4; ++tf) {
                int tokl = tf * 16 + (l & 15);
                float gm = fmaxf(fmaxf(a1w_s[0][tokl], a1w_s[1][tokl]),
                                 fmaxf(a1w_s[2][tokl], a1w_s[3][tokl]));
                m_run[tf] = fmaxf(m_run[tf], gm);
                float thr = m_run[tf] - MARGA;
#pragma unroll
                for (int f = 0; f < 4; ++f)
#pragma unroll
                    for (int r = 0; r < 4; ++r) {
                        float a = acc[f][tf][r];
                        if (a >= thr) {
                            int code = w * 256 + c * 64 + f * 16 + (l >> 4) * 4 + r;
                            int pos = atomicAdd(&cnt_s[tokl], 1);
                            if (pos < 16) {
                                lists_s[tokl * 16 + pos] = code;
                                avals_s[tokl * 16 + pos] = a;
                            }
                        }
                    }
            }
        }
    }

    __syncthreads();   // lists_s/avals_s visible to epilogue

    // epilogue: m_run == a1_final; wave 0 finalizes its tokens (identical to round 16)
    if (tid < 64) {
        int t = t0 + tid;
        int tfsel = tid >> 4;
        float a1v = (tfsel == 0) ? m_run[0] : (tfsel == 1) ? m_run[1]
                  : (tfsel == 2) ? m_run[2] : m_run[3];
        int ct_raw = cnt_s[tid];
        if (ct_raw > 16) {
            int pos = atomicAdd(wcnt, 1);
            wlist[pos] = t;
            cntg[t] = 999;
        } else {
            float thr = a1v - MARGA;
            int kept = 0, first = 0;
            for (int i = 0; i < ct_raw; ++i) {
                float av = avals_s[tid * 16 + i];
                if (av >= thr) {
                    int code = lists_s[tid * 16 + i];
                    if (kept == 0) first = code;
                    if (kept < 8) listsg[(size_t)t * 8 + kept] = code;
                    ++kept;
                }
            }
            if (kept == 1) {
                dout[IDX_OFF + t] = (float)first;
                loss2[t] = fmaf(-2.f, a1v, zsq[t]);
            } else {
                int pos = atomicAdd(wcnt, 1);
                wlist[pos] = t;
                cntg[t] = (kept > 8) ? 999 : kept;
            }
        }
    }
}

// ---------------- pairs: one LANE per (hard-token, candidate) pair ----------------
__global__ __launch_bounds__(256) void vq_pairs(const float* __restrict__ z,
                                                const float* __restrict__ emb,
                                                const float* __restrict__ zsq,
                                                const float* __restrict__ esq,
                                                const int* __restrict__ wcnt,
                                                const int* __restrict__ wlist,
                                                const int* __restrict__ cntg,
                                                const int* __restrict__ listsg,
                                                int* __restrict__ wcnt2,
                                                int* __restrict__ wlist2,
                                                float* __restrict__ paird) {
    const int n = wcnt[0];
    const int total = 8 * n;
    for (int p = blockIdx.x * 256 + threadIdx.x; p < total; p += gridDim.x * 256) {
        int q = p >> 3, slot = p & 7;
        int tok = wlist[q];
        int ct = cntg[tok];
        if (ct == 0 || ct > 8) {
            if (slot == 0) {
                int pos = atomicAdd(wcnt2, 1);
                if (pos < 4096) wlist2[pos] = tok;
            }
            continue;
        }
        if (slot >= ct) continue;
        int code = listsg[(size_t)tok * 8 + slot];
        paird[p] = faithful_d(z, emb, zsq[tok], esq[code], tok, code);
    }
}

// ---------------- pick: thread per hard token, lexicographic (d, code) argmin ----------------
__global__ __launch_bounds__(256) void vq_pick(const float* __restrict__ paird,
                                               const int* __restrict__ wcnt,
                                               const int* __restrict__ wlist,
                                               const int* __restrict__ cntg,
                                               const int* __restrict__ listsg,
                                               float* __restrict__ loss2,
                                               float* __restrict__ dout) {
    const int n = wcnt[0];
    for (int q = blockIdx.x * 256 + threadIdx.x; q < n; q += gridDim.x * 256) {
        int tok = wlist[q];
        int ct = cntg[tok];
        if (ct == 0 || ct > 8) continue;   // scan kernel owns these
        float db = paird[q * 8];
        int cb = listsg[(size_t)tok * 8];
        for (int i = 1; i < ct; ++i) {
            float d = paird[q * 8 + i];
            int c = listsg[(size_t)tok * 8 + i];
            if (d < db || (d == db && c < cb)) { db = d; cb = c; }
        }
        dout[IDX_OFF + tok] = (float)cb;
        loss2[tok] = db;
    }
}

// ---------------- decide (scan): BLOCK per token, full 1024 faithful scan (rare) ----------------
__global__ __launch_bounds__(256) void vq_decide_scan(const float* __restrict__ z,
                                                      const float* __restrict__ emb,
                                                      const float* __restrict__ zsq,
                                                      const float* __restrict__ esq,
                                                      const int* __restrict__ wcnt2,
                                                      const int* __restrict__ wlist2,
                                                      float* __restrict__ loss2,
                                                      float* __restrict__ dout) {
    __shared__ __align__(16) float zrow[DIM];
    __shared__ float dred[256];
    __shared__ int   ired[256];
    int n = wcnt2[0];
    if (n > 4096) n = 4096;
    const int tid = threadIdx.x;
    for (int job = blockIdx.x; job < n; job += 128) {
        int tok = wlist2[job];
        __syncthreads();
        if (tid < 64) ((float4*)zrow)[tid] = ((const float4*)(z + (size_t)tok * DIM))[tid];
        __syncthreads();
        float zq = zsq[tok];
        float a0 = 0.f, a1v = 0.f, a2 = 0.f, a3 = 0.f;
        const float4* e0 = (const float4*)(emb + (size_t)(tid      ) * DIM);
        const float4* e1 = (const float4*)(emb + (size_t)(tid + 256) * DIM);
        const float4* e2 = (const float4*)(emb + (size_t)(tid + 512) * DIM);
        const float4* e3 = (const float4*)(emb + (size_t)(tid + 768) * DIM);
#pragma unroll
        for (int seg = 0; seg < 4; ++seg) {
#pragma unroll
            for (int qq = 0; qq < 16; ++qq) {
                float4 a = ((float4*)zrow)[seg * 16 + qq];
                float4 b0 = e0[seg * 16 + qq], b1 = e1[seg * 16 + qq];
                float4 b2 = e2[seg * 16 + qq], b3 = e3[seg * 16 + qq];
                a0 = fmaf(a.x, b0.x, a0); a0 = fmaf(a.y, b0.y, a0);
                a0 = fmaf(a.z, b0.z, a0); a0 = fmaf(a.w, b0.w, a0);
                a1v = fmaf(a.x, b1.x, a1v); a1v = fmaf(a.y, b1.y, a1v);
                a1v = fmaf(a.z, b1.z, a1v); a1v = fmaf(a.w, b1.w, a1v);
                a2 = fmaf(a.x, b2.x, a2); a2 = fmaf(a.y, b2.y, a2);
                a2 = fmaf(a.z, b2.z, a2); a2 = fmaf(a.w, b2.w, a2);
                a3 = fmaf(a.x, b3.x, a3); a3 = fmaf(a.y, b3.y, a3);
                a3 = fmaf(a.z, b3.z, a3); a3 = fmaf(a.w, b3.w, a3);
            }
        }
        float d0 = (zq + esq[tid      ]) - 2.0f * a0;
        float d1 = (zq + esq[tid + 256]) - 2.0f * a1v;
        float d2 = (zq + esq[tid + 512]) - 2.0f * a2;
        float d3 = (zq + esq[tid + 768]) - 2.0f * a3;
        float db = d0; int cb = tid;
        if (d1 < db) { db = d1; cb = tid + 256; }
        if (d2 < db) { db = d2; cb = tid + 512; }
        if (d3 < db) { db = d3; cb = tid + 768; }
        dred[tid] = db; ired[tid] = cb;
        __syncthreads();
        for (int step = 128; step >= 1; step >>= 1) {
            if (tid < step) {
                float od = dred[tid + step]; int oi = ired[tid + step];
                if (od < dred[tid] || (od == dred[tid] && oi < ired[tid])) {
                    dred[tid] = od; ired[tid] = oi;
                }
            }
            __syncthreads();
        }
        if (tid == 0) {
            dout[IDX_OFF + tok] = (float)ired[0];
            loss2[tok] = dred[0];
        }
    }
}

// ---------------- loss reduction (fixed order) ----------------
__global__ __launch_bounds__(256) void vq_sum(const float* __restrict__ loss2,
                                              float* __restrict__ part) {
    __shared__ float ws[4];
    float s = 0.f;
#pragma unroll
    for (int q = 0; q < 4; ++q)
        s += loss2[blockIdx.x * 1024 + q * 256 + threadIdx.x];
#pragma unroll
    for (int m = 1; m < 64; m <<= 1) s += __shfl_xor(s, m, 64);
    if ((threadIdx.x & 63) == 0) ws[threadIdx.x >> 6] = s;
    __syncthreads();
    if (threadIdx.x == 0) part[blockIdx.x] = ws[0] + ws[1] + ws[2] + ws[3];
}

__global__ __launch_bounds__(64) void vq_final(const float* __restrict__ part,
                                               float* __restrict__ dout) {
    double s = (double)part[threadIdx.x];
#pragma unroll
    for (int m = 1; m < 64; m <<= 1) s += __shfl_xor(s, m, 64);
    if (threadIdx.x == 0) dout[LOSS_OFF] = (float)(s * 1.25 / 16777216.0);
}

// ---------------- gather z_q rows ----------------
__global__ __launch_bounds__(256) void vq_gather(const float* __restrict__ emb,
                                                 float* __restrict__ dout) {
    const int w = threadIdx.x >> 6, l = threadIdx.x & 63;
    for (int tok = blockIdx.x * 4 + w; tok < NTOK; tok += 2048 * 4) {
        int widx = (int)dout[IDX_OFF + tok];
        float4 ev = *(const float4*)&emb[(size_t)widx * DIM + l * 4];
        *(float4*)&dout[(size_t)tok * DIM + l * 4] = ev;
    }
}

extern "C" void kernel_launch(void* const* d_in, const int* in_sizes, int n_in,
                              void* d_out, int out_size, void* d_ws, size_t ws_size,
                              hipStream_t stream) {
    const float* z   = (const float*)d_in[0];
    const float* emb = (const float*)d_in[1];
    float* out = (float*)d_out;

    float* zsq   = out + SC_ZSQ;
    float* loss2 = out + SC_LOSS2;
    float* esq   = out + SC_ESQ;
    float* esqnh = out + SC_ESQNH;
    float* part  = out + SC_PART;
    int*   wcnt  = (int*)(out + SC_WCNT);
    int*   wcnt2 = (int*)(out + SC_WCNT2);
    int*   cntg  = (int*)(out + SC_CNTG);
    int*   listsg= (int*)(out + SC_LISTS);
    int*   wlist = (int*)(out + SC_WLIST);
    int*   wlist2= (int*)(out + SC_WLIST2);
    float* paird = out + SC_PAIRD;
    unsigned short* img  = (unsigned short*)(out + SC_EHIMG);
    unsigned short* zimg = (unsigned short*)(out + SC_ZIMG);

    vq_prep_emb <<<64,   256, 0, stream>>>(emb, esq, esqnh, img, wcnt, wcnt2);
    vq_prep_z   <<<4096, 256, 0, stream>>>(z, zsq, zimg);
    vq_gemm     <<<1024, 256, 0, stream>>>(zimg, img, esqnh, zsq, wcnt, wlist, cntg, listsg, loss2, out);
    vq_pairs    <<<512,  256, 0, stream>>>(z, emb, zsq, esq, wcnt, wlist, cntg, listsg, wcnt2, wlist2, paird);
    vq_pick     <<<256,  256, 0, stream>>>(paird, wcnt, wlist, cntg, listsg, loss2, out);
    vq_decide_scan<<<128, 256, 0, stream>>>(z, emb, zsq, esq, wcnt2, wlist2, loss2, out);
    vq_sum      <<<64,   256, 0, stream>>>(loss2, part);
    vq_final    <<<1,    64,  0, stream>>>(part, out);
    vq_gather   <<<2048, 256, 0, stream>>>(emb, out);
}